// Round 6
// baseline (653.859 us; speedup 1.0000x reference)
//
#include <hip/hip_runtime.h>
#include <hip/hip_bf16.h>
#include <stdint.h>

#define NG 128
#define EPSI 1e-5f

typedef __attribute__((ext_vector_type(8))) __bf16 bf16x8;
typedef __attribute__((ext_vector_type(4))) float f32x4;

union ABFrag { bf16x8 v; unsigned short u[8]; uint4 q; };
union BF8 { bf16x8 v; uint4 q; };

__device__ __forceinline__ unsigned short f2b(float f){
  union { float f; unsigned int i; } v; v.f = f;
  unsigned int r = v.i + 0x7fffu + ((v.i >> 16) & 1u);
  return (unsigned short)(r >> 16);
}

// ---------------- prep: bf16 conversions (frag order), graph hist, node hist ----------------
__global__ void kprep(const float* __restrict__ emb, const float* __restrict__ W1,
                      const float* __restrict__ W2,
                      const int* __restrict__ ei, const int* __restrict__ batch,
                      __bf16* __restrict__ embb, unsigned short* __restrict__ WcF,
                      unsigned short* __restrict__ W2F, unsigned int* __restrict__ hist,
                      unsigned int* __restrict__ nodeh, int N, int E){
  __shared__ unsigned int h[NG];
  for (int i = threadIdx.x; i < NG; i += 256) h[i] = 0;
  __syncthreads();
  int idx = blockIdx.x * 256 + threadIdx.x;
  int stride = gridDim.x * 256;
  int embCnt4 = N * 16;  // float4 groups
  for (int i = idx; i < embCnt4; i += stride){
    float4 v = *(const float4*)(emb + (size_t)i * 4);
    __bf16 o[4]; o[0] = (__bf16)v.x; o[1] = (__bf16)v.y; o[2] = (__bf16)v.z; o[3] = (__bf16)v.w;
    *(ushort4*)(embb + (size_t)i * 4) = *(ushort4*)o;
  }
  for (int i = idx; i < 32 * 2 * 64 * 8; i += stride){
    int j = i & 7, lane = (i >> 3) & 63, ks = (i >> 9) & 1, tn = i >> 10;
    int quad = lane >> 4, l15 = lane & 15;
    int k = ks * 32 + quad * 8 + j;
    int n = tn * 16 + l15;
    float wv = (n < 256) ? W1[k * 256 + n] : W1[(k + 64) * 256 + (n - 256)];
    WcF[i] = f2b(wv);
  }
  for (int i = idx; i < 4 * 8 * 64 * 8; i += stride){
    int j = i & 7, lane = (i >> 3) & 63, ks = (i >> 9) & 7, w = i >> 12;
    int quad = lane >> 4, l15 = lane & 15;
    W2F[i] = f2b(W2[(ks * 32 + quad * 8 + j) * 64 + w * 16 + l15]);
  }
  for (int e = idx; e < E; e += stride){
    int cn = ei[e];
    atomicAdd(&h[batch[cn]], 1u);
    atomicAdd(&nodeh[cn], 1u);
  }
  __syncthreads();
  for (int i = threadIdx.x; i < NG; i += 256)
    if (h[i]) atomicAdd(&hist[i], h[i]);
}

// ---------------- exclusive scan over node histogram (single block) ----------------
__global__ void kscan(const unsigned int* __restrict__ nodeh, unsigned int* __restrict__ ncursor,
                      int N){
  __shared__ unsigned int ts[1024];
  int t = threadIdx.x;
  int chunk = (N + 1023) / 1024;
  int a = t * chunk, b = min(N, a + chunk);
  unsigned int s = 0;
  for (int i = a; i < b; ++i) s += nodeh[i];
  ts[t] = s;
  __syncthreads();
  if (t == 0){
    unsigned int run = 0;
    for (int i = 0; i < 1024; ++i){ unsigned int v = ts[i]; ts[i] = run; run += v; }
  }
  __syncthreads();
  unsigned int base = ts[t];
  for (int i = a; i < b; ++i){ ncursor[i] = base; base += nodeh[i]; }
}

// ------- fused: scatter (blocks [0,scatBlocks)) + GEMM1 (rest) -------
// einfo[p] = {col_node, row_node, graph, orig_edge}, p sorted by col node (=> by graph)
// PQ[N,512] = embb[N,64] @ W1cat[64,512] (+b1 on P cols)
__global__ void __launch_bounds__(256) kfused(const int* __restrict__ ei,
    const int* __restrict__ batch, unsigned int* __restrict__ ncursor,
    int4* __restrict__ einfo, int E,
    const __bf16* __restrict__ embb, const unsigned short* __restrict__ WcF,
    const float* __restrict__ b1, __bf16* __restrict__ PQh, int Nn, int scatBlocks){
  int b = blockIdx.x;
  if (b < scatBlocks){
    int e = b * 256 + threadIdx.x;
    if (e < E){
      int cn = ei[e], rn = ei[E + e];
      int g = batch[cn];
      unsigned int p = atomicAdd(&ncursor[cn], 1u);
      einfo[p] = make_int4(cn, rn, g, e);
    }
    return;
  }
  int gb = b - scatBlocks;
  int wave = threadIdx.x >> 6, lane = threadIdx.x & 63;
  int quad = lane >> 4, l15 = lane & 15;
  int t = gb * 4 + wave;
  int tmmax = (Nn + 15) >> 4;
  int tm = t >> 5, tn = t & 31;
  if (tm >= tmmax) return;
  int m = tm * 16 + l15; if (m >= Nn) m = Nn - 1;
  f32x4 acc = {0.f, 0.f, 0.f, 0.f};
  #pragma unroll
  for (int ks = 0; ks < 2; ++ks){
    ABFrag a, bfr;
    a.q = *(const uint4*)(embb + (size_t)m * 64 + ks * 32 + quad * 8);
    bfr.q = *(const uint4*)(WcF + ((size_t)(tn * 2 + ks) * 64 + lane) * 8);
    acc = __builtin_amdgcn_mfma_f32_16x16x32_bf16(a.v, bfr.v, acc, 0, 0, 0);
  }
  int col = tn * 16 + l15;
  float bias = (col < 256) ? b1[col] : 0.0f;
  #pragma unroll
  for (int r = 0; r < 4; ++r){
    int rowg = tm * 16 + quad * 4 + r;
    if (rowg < Nn) PQh[(size_t)rowg * 512 + col] = (__bf16)(acc[r] + bias);
  }
}

// ------- stats over y1 = P[col]+Q[row]; 512-edge chunk/block, LDS accumulate, 4-deep MLP -----
__global__ void __launch_bounds__(256) kstats1(const __bf16* __restrict__ PQh,
                        const int4* __restrict__ einfo,
                        int E, float* __restrict__ sum1, float* __restrict__ sq1){
  __shared__ float lsum[8][256];
  __shared__ float lsq[8][256];
  int tid = threadIdx.x;
  for (int i = tid; i < 8 * 256; i += 256){ ((float*)lsum)[i] = 0.f; ((float*)lsq)[i] = 0.f; }
  __syncthreads();
  int i0 = blockIdx.x * 512;
  int i1 = min(E, i0 + 512);
  int gfirst = einfo[i0].z;
  int eo = tid >> 5;          // 8 edge slots
  int c8 = (tid & 31) * 8;    // 8-channel slice
  float s[8], q[8];
  #pragma unroll
  for (int t = 0; t < 8; ++t){ s[t] = 0.f; q[t] = 0.f; }
  int cur = -1;
  auto flushreg = [&](){
    if (cur >= 0){
      unsigned slot = (unsigned)(cur - gfirst);
      if (slot < 8u){
        #pragma unroll
        for (int t = 0; t < 8; ++t){
          atomicAdd(&lsum[slot][c8 + t], s[t]);
          atomicAdd(&lsq[slot][c8 + t], q[t]);
        }
      } else {
        #pragma unroll
        for (int t = 0; t < 8; ++t){
          atomicAdd(&sum1[cur * 256 + c8 + t], s[t]);
          atomicAdd(&sq1[cur * 256 + c8 + t], q[t]);
        }
      }
      #pragma unroll
      for (int t = 0; t < 8; ++t){ s[t] = 0.f; q[t] = 0.f; }
    }
  };
  for (int base = i0 + eo; base < i1; base += 32){
    int4 ev[4];
    #pragma unroll
    for (int k = 0; k < 4; ++k){
      int p = base + k * 8;
      ev[k] = (p < i1) ? einfo[p] : make_int4(0, 0, -1, 0);
    }
    BF8 pu[4], qu[4];
    #pragma unroll
    for (int k = 0; k < 4; ++k){
      pu[k].v = *(const bf16x8*)(PQh + (size_t)ev[k].x * 512 + c8);
      qu[k].v = *(const bf16x8*)(PQh + (size_t)ev[k].y * 512 + 256 + c8);
    }
    #pragma unroll
    for (int k = 0; k < 4; ++k){
      int g = ev[k].z;
      if (g >= 0){
        if (g != cur){ flushreg(); cur = g; }
        #pragma unroll
        for (int t = 0; t < 8; ++t){
          float y = (float)pu[k].v[t] + (float)qu[k].v[t];
          s[t] += y; q[t] = fmaf(y, y, q[t]);
        }
      }
    }
  }
  flushreg();
  __syncthreads();
  for (int i = tid; i < 8 * 256; i += 256){
    int slot = i >> 8, ch = i & 255;
    float vs = lsum[slot][ch], vq = lsq[slot][ch];
    if (vs != 0.f || vq != 0.f){
      int g = gfirst + slot;
      atomicAdd(&sum1[g * 256 + ch], vs);
      atomicAdd(&sq1[g * 256 + ch], vq);
    }
  }
}

// kfin: emit rstd and nmr = -mean*rstd  (consumer does h = fma(y, rstd, nmr))
__global__ void kfin(const float* __restrict__ sum, const float* __restrict__ sq,
                     const unsigned int* __restrict__ hist,
                     float* __restrict__ rstdA, float* __restrict__ nmrA, int C){
  int i = blockIdx.x * blockDim.x + threadIdx.x;
  if (i >= NG * C) return;
  int g = i / C;
  float cnt = fmaxf((float)hist[g], 1.0f);
  float m = sum[i] / cnt;
  float v = sq[i] / cnt - m * m;
  float r = rsqrtf(fmaxf(v, 0.f) + EPSI);
  rstdA[i] = r;
  nmrA[i] = -m * r;
}

// ------- fused: norm+ReLU L1 -> GEMM2 -> y2 (64-edge tiles, fma-norm, native bf16 cvt) -----
__global__ void __launch_bounds__(256) kmain(const __bf16* __restrict__ PQh,
    const unsigned short* __restrict__ W2F, const int4* __restrict__ einfo,
    const float* __restrict__ rstd1, const float* __restrict__ nmr1,
    const float* __restrict__ b2, __bf16* __restrict__ y2h, int E){
  __shared__ __bf16 tileA[64][264];  // stride 264: 2-way LDS aliasing only (free)
  int wave = threadIdx.x >> 6, lane = threadIdx.x & 63;
  int quad = lane >> 4, l15 = lane & 15;
  int eo = lane >> 5;         // pair slot for stage-1
  int c8 = (lane & 31) * 8;   // 8-channel slice for stage-1
  ABFrag bk[8];
  #pragma unroll
  for (int ks = 0; ks < 8; ++ks)
    bk[ks].q = *(const uint4*)(W2F + ((size_t)(wave * 8 + ks) * 64 + lane) * 8);
  int cc = wave * 16 + l15;
  float bias2 = b2[cc];
  int nt = (E + 63) >> 6;
  for (int tb = blockIdx.x; tb < nt; tb += gridDim.x){
    int p0 = tb * 64;
    __syncthreads();
    if (p0 + 64 <= E){
      #pragma unroll
      for (int j = 0; j < 8; ++j){
        int le = wave * 16 + j * 2 + eo;
        int4 ev = einfo[p0 + le];
        BF8 pu, qu, hv;
        pu.v = *(const bf16x8*)(PQh + (size_t)ev.x * 512 + c8);
        qu.v = *(const bf16x8*)(PQh + (size_t)ev.y * 512 + 256 + c8);
        float rr[8], nn[8];
        *(float4*)&rr[0] = *(const float4*)(rstd1 + ev.z * 256 + c8);
        *(float4*)&rr[4] = *(const float4*)(rstd1 + ev.z * 256 + c8 + 4);
        *(float4*)&nn[0] = *(const float4*)(nmr1 + ev.z * 256 + c8);
        *(float4*)&nn[4] = *(const float4*)(nmr1 + ev.z * 256 + c8 + 4);
        #pragma unroll
        for (int t = 0; t < 8; ++t){
          float y = (float)pu.v[t] + (float)qu.v[t];
          hv.v[t] = (__bf16)fmaxf(0.f, fmaf(y, rr[t], nn[t]));
        }
        *(uint4*)&tileA[le][c8] = hv.q;
      }
    } else {
      #pragma unroll
      for (int j = 0; j < 8; ++j){
        int le = wave * 16 + j * 2 + eo;
        int p = p0 + le;
        BF8 hv; hv.q = make_uint4(0, 0, 0, 0);
        if (p < E){
          int4 ev = einfo[p];
          BF8 pu, qu;
          pu.v = *(const bf16x8*)(PQh + (size_t)ev.x * 512 + c8);
          qu.v = *(const bf16x8*)(PQh + (size_t)ev.y * 512 + 256 + c8);
          float rr[8], nn[8];
          *(float4*)&rr[0] = *(const float4*)(rstd1 + ev.z * 256 + c8);
          *(float4*)&rr[4] = *(const float4*)(rstd1 + ev.z * 256 + c8 + 4);
          *(float4*)&nn[0] = *(const float4*)(nmr1 + ev.z * 256 + c8);
          *(float4*)&nn[4] = *(const float4*)(nmr1 + ev.z * 256 + c8 + 4);
          #pragma unroll
          for (int t = 0; t < 8; ++t){
            float y = (float)pu.v[t] + (float)qu.v[t];
            hv.v[t] = (__bf16)fmaxf(0.f, fmaf(y, rr[t], nn[t]));
          }
        }
        *(uint4*)&tileA[le][c8] = hv.q;
      }
    }
    __syncthreads();
    f32x4 acc[4];
    #pragma unroll
    for (int eg = 0; eg < 4; ++eg){ acc[eg][0]=0.f; acc[eg][1]=0.f; acc[eg][2]=0.f; acc[eg][3]=0.f; }
    #pragma unroll
    for (int eg = 0; eg < 4; ++eg)
      #pragma unroll
      for (int ks = 0; ks < 8; ++ks){
        ABFrag a;
        a.q = *(const uint4*)&tileA[eg * 16 + l15][ks * 32 + quad * 8];
        acc[eg] = __builtin_amdgcn_mfma_f32_16x16x32_bf16(a.v, bk[ks].v, acc[eg], 0, 0, 0);
      }
    #pragma unroll
    for (int eg = 0; eg < 4; ++eg)
      #pragma unroll
      for (int r = 0; r < 4; ++r){
        int p = p0 + eg * 16 + quad * 4 + r;
        if (p < E) y2h[(size_t)p * 64 + cc] = (__bf16)(acc[eg][r] + bias2);
      }
  }
}

// ------- stats over y2; contiguous 1024-edge chunk/block, LDS accumulate -------
__global__ void __launch_bounds__(256) kstats2(const __bf16* __restrict__ y2h,
                        const int4* __restrict__ einfo,
                        int E, float* __restrict__ sum2, float* __restrict__ sq2){
  __shared__ float lsum[8][64];
  __shared__ float lsq[8][64];
  int tid = threadIdx.x;
  for (int i = tid; i < 8 * 64; i += 256){ ((float*)lsum)[i] = 0.f; ((float*)lsq)[i] = 0.f; }
  __syncthreads();
  int i0 = blockIdx.x * 1024;
  int i1 = min(E, i0 + 1024);
  int gfirst = einfo[i0].z;
  int eo = tid >> 3;         // 32 edge slots
  int c8 = (tid & 7) * 8;    // 8-channel slice
  float s[8], q[8];
  #pragma unroll
  for (int t = 0; t < 8; ++t){ s[t] = 0.f; q[t] = 0.f; }
  int cur = -1;
  auto flushreg = [&](){
    if (cur >= 0){
      unsigned slot = (unsigned)(cur - gfirst);
      if (slot < 8u){
        #pragma unroll
        for (int t = 0; t < 8; ++t){
          atomicAdd(&lsum[slot][c8 + t], s[t]);
          atomicAdd(&lsq[slot][c8 + t], q[t]);
        }
      } else {
        #pragma unroll
        for (int t = 0; t < 8; ++t){
          atomicAdd(&sum2[cur * 64 + c8 + t], s[t]);
          atomicAdd(&sq2[cur * 64 + c8 + t], q[t]);
        }
      }
      #pragma unroll
      for (int t = 0; t < 8; ++t){ s[t] = 0.f; q[t] = 0.f; }
    }
  };
  for (int p = i0 + eo; p < i1; p += 64){
    int g0 = einfo[p].z;
    int p2 = p + 32;
    int g1 = (p2 < i1) ? einfo[p2].z : -1;
    BF8 y0, y1;
    y0.v = *(const bf16x8*)(y2h + (size_t)p * 64 + c8);
    y1.q = make_uint4(0, 0, 0, 0);
    if (g1 >= 0) y1.v = *(const bf16x8*)(y2h + (size_t)p2 * 64 + c8);
    if (g0 != cur){ flushreg(); cur = g0; }
    #pragma unroll
    for (int t = 0; t < 8; ++t){
      float y = (float)y0.v[t];
      s[t] += y; q[t] = fmaf(y, y, q[t]);
    }
    if (g1 >= 0){
      if (g1 != cur){ flushreg(); cur = g1; }
      #pragma unroll
      for (int t = 0; t < 8; ++t){
        float y = (float)y1.v[t];
        s[t] += y; q[t] = fmaf(y, y, q[t]);
      }
    }
  }
  flushreg();
  __syncthreads();
  for (int i = tid; i < 8 * 64; i += 256){
    int slot = i >> 6, ch = i & 63;
    float vs = lsum[slot][ch], vq = lsq[slot][ch];
    if (vs != 0.f || vq != 0.f){
      int g = gfirst + slot;
      atomicAdd(&sum2[g * 64 + ch], vs);
      atomicAdd(&sq2[g * 64 + ch], vq);
    }
  }
}

// ------- final: norm+ReLU L2 -> GEMV W3 -> scatter; 8 lanes per edge + shuffle reduce -------
__global__ void kfinal(const __bf16* __restrict__ y2h, const int4* __restrict__ einfo,
                       const float* __restrict__ rstd2, const float* __restrict__ nmr2,
                       const float* __restrict__ W3, const float* __restrict__ b3,
                       float* __restrict__ out, int E){
  int sub = threadIdx.x & 7;
  int c8 = sub * 8;
  float w3r[8];
  #pragma unroll
  for (int t = 0; t < 8; ++t) w3r[t] = W3[c8 + t];
  float b3v = b3[0];
  int step = (gridDim.x * blockDim.x) >> 3;
  for (int i = (blockIdx.x * blockDim.x + threadIdx.x) >> 3; i < E; i += step){
    int4 ev = einfo[i];
    BF8 yv; yv.v = *(const bf16x8*)(y2h + (size_t)i * 64 + c8);
    float rr[8], nn[8];
    *(float4*)&rr[0] = *(const float4*)(rstd2 + ev.z * 64 + c8);
    *(float4*)&rr[4] = *(const float4*)(rstd2 + ev.z * 64 + c8 + 4);
    *(float4*)&nn[0] = *(const float4*)(nmr2 + ev.z * 64 + c8);
    *(float4*)&nn[4] = *(const float4*)(nmr2 + ev.z * 64 + c8 + 4);
    float a = 0.f;
    #pragma unroll
    for (int t = 0; t < 8; ++t)
      a += fmaxf(0.f, fmaf((float)yv.v[t], rr[t], nn[t])) * w3r[t];
    a += __shfl_xor(a, 1);
    a += __shfl_xor(a, 2);
    a += __shfl_xor(a, 4);
    if (sub == 0) out[ev.w] = a + b3v;
  }
}

extern "C" void kernel_launch(void* const* d_in, const int* in_sizes, int n_in,
                              void* d_out, int out_size, void* d_ws, size_t ws_size,
                              hipStream_t stream){
  const float* emb  = (const float*)d_in[0];
  const int*   ei   = (const int*)d_in[1];
  const int*   batch= (const int*)d_in[2];
  const float* W1   = (const float*)d_in[3];
  const float* b1   = (const float*)d_in[4];
  const float* W2   = (const float*)d_in[5];
  const float* b2   = (const float*)d_in[6];
  const float* W3   = (const float*)d_in[7];
  const float* b3   = (const float*)d_in[8];
  int N = in_sizes[0] / 64;
  int E = in_sizes[1] / 2;
  float* out = (float*)d_out;

  char* w = (char*)d_ws;
  size_t off = 0;
  auto nxt = [&](size_t bytes) -> char* {
    char* p = w + off;
    off = (off + bytes + 255) & ~(size_t)255;
    return p;
  };
  __bf16* embb = (__bf16*)nxt((size_t)N * 64 * 2);
  unsigned short* WcF  = (unsigned short*)nxt(32 * 2 * 64 * 8 * 2);
  unsigned short* W2F  = (unsigned short*)nxt(4 * 8 * 64 * 8 * 2);
  __bf16* PQh  = (__bf16*)nxt((size_t)N * 512 * 2);
  __bf16* y2h  = (__bf16*)nxt((size_t)E * 64 * 2);
  int4* einfo = (int4*)nxt((size_t)E * 16);
  float* rstd1 = (float*)nxt(NG * 256 * 4);
  float* nmr1  = (float*)nxt(NG * 256 * 4);
  float* rstd2 = (float*)nxt(NG * 64 * 4);
  float* nmr2  = (float*)nxt(NG * 64 * 4);
  unsigned int* ncursor = (unsigned int*)nxt((size_t)N * 4);
  // zero-init region (contiguous, one memset)
  char* zbase = w + off;
  unsigned int* hist  = (unsigned int*)nxt(NG * 4);
  unsigned int* nodeh = (unsigned int*)nxt((size_t)N * 4);
  float* sum1 = (float*)nxt(NG * 256 * 4);
  float* sq1  = (float*)nxt(NG * 256 * 4);
  float* sum2 = (float*)nxt(NG * 64 * 4);
  float* sq2  = (float*)nxt(NG * 64 * 4);
  size_t zbytes = (size_t)((w + off) - zbase);
  hipMemsetAsync(zbase, 0, zbytes, stream);

  kprep<<<2048, 256, 0, stream>>>(emb, W1, W2, ei, batch, embb, WcF, W2F, hist, nodeh, N, E);
  kscan<<<1, 1024, 0, stream>>>(nodeh, ncursor, N);
  {
    int scatBlocks = (E + 255) / 256;
    int gemmBlocks = (((N + 15) / 16) * 32 + 3) / 4;
    kfused<<<scatBlocks + gemmBlocks, 256, 0, stream>>>(ei, batch, ncursor, einfo, E,
                                                        embb, WcF, b1, PQh, N, scatBlocks);
  }
  kstats1<<<(E + 511) / 512, 256, 0, stream>>>(PQh, einfo, E, sum1, sq1);
  kfin<<<(NG * 256 + 255) / 256, 256, 0, stream>>>(sum1, sq1, hist, rstd1, nmr1, 256);
  kmain<<<2048, 256, 0, stream>>>(PQh, W2F, einfo, rstd1, nmr1, b2, y2h, E);
  kstats2<<<(E + 1023) / 1024, 256, 0, stream>>>(y2h, einfo, E, sum2, sq2);
  kfin<<<(NG * 64 + 255) / 256, 256, 0, stream>>>(sum2, sq2, hist, rstd2, nmr2, 64);
  kfinal<<<2048, 256, 0, stream>>>(y2h, einfo, rstd2, nmr2, W3, b3, out, E);
}

// Round 7
// 649.615 us; speedup vs baseline: 1.0065x; 1.0065x over previous
//
#include <hip/hip_runtime.h>
#include <hip/hip_bf16.h>
#include <stdint.h>

#define NG 128
#define EPSI 1e-5f

typedef __attribute__((ext_vector_type(8))) __bf16 bf16x8;
typedef __attribute__((ext_vector_type(4))) float f32x4;

union ABFrag { bf16x8 v; unsigned short u[8]; uint4 q; };
union BF8 { bf16x8 v; uint4 q; };

__device__ __forceinline__ unsigned short f2b(float f){
  union { float f; unsigned int i; } v; v.f = f;
  unsigned int r = v.i + 0x7fffu + ((v.i >> 16) & 1u);
  return (unsigned short)(r >> 16);
}

// ---------------- prep: bf16 conversions (frag order), graph hist, node hist ----------------
__global__ void kprep(const float* __restrict__ emb, const float* __restrict__ W1,
                      const float* __restrict__ W2,
                      const int* __restrict__ ei, const int* __restrict__ batch,
                      __bf16* __restrict__ embb, unsigned short* __restrict__ WcF,
                      unsigned short* __restrict__ W2F, unsigned int* __restrict__ hist,
                      unsigned int* __restrict__ nodeh, int N, int E){
  __shared__ unsigned int h[NG];
  for (int i = threadIdx.x; i < NG; i += 256) h[i] = 0;
  __syncthreads();
  int idx = blockIdx.x * 256 + threadIdx.x;
  int stride = gridDim.x * 256;
  int embCnt4 = N * 16;  // float4 groups
  for (int i = idx; i < embCnt4; i += stride){
    float4 v = *(const float4*)(emb + (size_t)i * 4);
    __bf16 o[4]; o[0] = (__bf16)v.x; o[1] = (__bf16)v.y; o[2] = (__bf16)v.z; o[3] = (__bf16)v.w;
    *(ushort4*)(embb + (size_t)i * 4) = *(ushort4*)o;
  }
  for (int i = idx; i < 32 * 2 * 64 * 8; i += stride){
    int j = i & 7, lane = (i >> 3) & 63, ks = (i >> 9) & 1, tn = i >> 10;
    int quad = lane >> 4, l15 = lane & 15;
    int k = ks * 32 + quad * 8 + j;
    int n = tn * 16 + l15;
    float wv = (n < 256) ? W1[k * 256 + n] : W1[(k + 64) * 256 + (n - 256)];
    WcF[i] = f2b(wv);
  }
  for (int i = idx; i < 4 * 8 * 64 * 8; i += stride){
    int j = i & 7, lane = (i >> 3) & 63, ks = (i >> 9) & 7, w = i >> 12;
    int quad = lane >> 4, l15 = lane & 15;
    W2F[i] = f2b(W2[(ks * 32 + quad * 8 + j) * 64 + w * 16 + l15]);
  }
  for (int e = idx; e < E; e += stride){
    int cn = ei[e];
    atomicAdd(&h[batch[cn]], 1u);
    atomicAdd(&nodeh[cn], 1u);
  }
  __syncthreads();
  for (int i = threadIdx.x; i < NG; i += 256)
    if (h[i]) atomicAdd(&hist[i], h[i]);
}

// ---------------- exclusive scan over node histogram (single block) ----------------
__global__ void kscan(const unsigned int* __restrict__ nodeh, unsigned int* __restrict__ ncursor,
                      int N){
  __shared__ unsigned int ts[1024];
  int t = threadIdx.x;
  int chunk = (N + 1023) / 1024;
  int a = t * chunk, b = min(N, a + chunk);
  unsigned int s = 0;
  for (int i = a; i < b; ++i) s += nodeh[i];
  ts[t] = s;
  __syncthreads();
  if (t == 0){
    unsigned int run = 0;
    for (int i = 0; i < 1024; ++i){ unsigned int v = ts[i]; ts[i] = run; run += v; }
  }
  __syncthreads();
  unsigned int base = ts[t];
  for (int i = a; i < b; ++i){ ncursor[i] = base; base += nodeh[i]; }
}

// ------- fused: scatter (blocks [0,scatBlocks)) + GEMM1 (rest) -------
__global__ void __launch_bounds__(256) kfused(const int* __restrict__ ei,
    const int* __restrict__ batch, unsigned int* __restrict__ ncursor,
    int4* __restrict__ einfo, int E,
    const __bf16* __restrict__ embb, const unsigned short* __restrict__ WcF,
    const float* __restrict__ b1, __bf16* __restrict__ PQh, int Nn, int scatBlocks){
  int b = blockIdx.x;
  if (b < scatBlocks){
    int e = b * 256 + threadIdx.x;
    if (e < E){
      int cn = ei[e], rn = ei[E + e];
      int g = batch[cn];
      unsigned int p = atomicAdd(&ncursor[cn], 1u);
      einfo[p] = make_int4(cn, rn, g, e);
    }
    return;
  }
  int gb = b - scatBlocks;
  int wave = threadIdx.x >> 6, lane = threadIdx.x & 63;
  int quad = lane >> 4, l15 = lane & 15;
  int t = gb * 4 + wave;
  int tmmax = (Nn + 15) >> 4;
  int tm = t >> 5, tn = t & 31;
  if (tm >= tmmax) return;
  int m = tm * 16 + l15; if (m >= Nn) m = Nn - 1;
  f32x4 acc = {0.f, 0.f, 0.f, 0.f};
  #pragma unroll
  for (int ks = 0; ks < 2; ++ks){
    ABFrag a, bfr;
    a.q = *(const uint4*)(embb + (size_t)m * 64 + ks * 32 + quad * 8);
    bfr.q = *(const uint4*)(WcF + ((size_t)(tn * 2 + ks) * 64 + lane) * 8);
    acc = __builtin_amdgcn_mfma_f32_16x16x32_bf16(a.v, bfr.v, acc, 0, 0, 0);
  }
  int col = tn * 16 + l15;
  float bias = (col < 256) ? b1[col] : 0.0f;
  #pragma unroll
  for (int r = 0; r < 4; ++r){
    int rowg = tm * 16 + quad * 4 + r;
    if (rowg < Nn) PQh[(size_t)rowg * 512 + col] = (__bf16)(acc[r] + bias);
  }
}

// ------- stats over y1 = P[col]+Q[row]; 512-edge chunk/block, LDS accumulate, 8-deep MLP -----
__global__ void __launch_bounds__(256) kstats1(const __bf16* __restrict__ PQh,
                        const int4* __restrict__ einfo,
                        int E, float* __restrict__ sum1, float* __restrict__ sq1){
  __shared__ float lsum[8][256];
  __shared__ float lsq[8][256];
  int tid = threadIdx.x;
  for (int i = tid; i < 8 * 256; i += 256){ ((float*)lsum)[i] = 0.f; ((float*)lsq)[i] = 0.f; }
  __syncthreads();
  int i0 = blockIdx.x * 512;
  int i1 = min(E, i0 + 512);
  int gfirst = einfo[i0].z;
  int eo = tid >> 5;          // 8 edge slots
  int c8 = (tid & 31) * 8;    // 8-channel slice
  float s[8], q[8];
  #pragma unroll
  for (int t = 0; t < 8; ++t){ s[t] = 0.f; q[t] = 0.f; }
  int cur = -1;
  auto flushreg = [&](){
    if (cur >= 0){
      unsigned slot = (unsigned)(cur - gfirst);
      if (slot < 8u){
        #pragma unroll
        for (int t = 0; t < 8; ++t){
          atomicAdd(&lsum[slot][c8 + t], s[t]);
          atomicAdd(&lsq[slot][c8 + t], q[t]);
        }
      } else {
        #pragma unroll
        for (int t = 0; t < 8; ++t){
          atomicAdd(&sum1[cur * 256 + c8 + t], s[t]);
          atomicAdd(&sq1[cur * 256 + c8 + t], q[t]);
        }
      }
      #pragma unroll
      for (int t = 0; t < 8; ++t){ s[t] = 0.f; q[t] = 0.f; }
    }
  };
  for (int base = i0 + eo; base < i1; base += 64){
    int4 ev[8];
    #pragma unroll
    for (int k = 0; k < 8; ++k){
      int p = base + k * 8;
      ev[k] = (p < i1) ? einfo[p] : make_int4(0, 0, -1, 0);
    }
    BF8 pu[8], qu[8];
    #pragma unroll
    for (int k = 0; k < 8; ++k){
      pu[k].v = *(const bf16x8*)(PQh + (size_t)ev[k].x * 512 + c8);
      qu[k].v = *(const bf16x8*)(PQh + (size_t)ev[k].y * 512 + 256 + c8);
    }
    #pragma unroll
    for (int k = 0; k < 8; ++k){
      int g = ev[k].z;
      if (g >= 0){
        if (g != cur){ flushreg(); cur = g; }
        #pragma unroll
        for (int t = 0; t < 8; ++t){
          float y = (float)pu[k].v[t] + (float)qu[k].v[t];
          s[t] += y; q[t] = fmaf(y, y, q[t]);
        }
      }
    }
  }
  flushreg();
  __syncthreads();
  for (int i = tid; i < 8 * 256; i += 256){
    int slot = i >> 8, ch = i & 255;
    float vs = lsum[slot][ch], vq = lsq[slot][ch];
    if (vs != 0.f || vq != 0.f){
      int g = gfirst + slot;
      if (g < NG){
        atomicAdd(&sum1[g * 256 + ch], vs);
        atomicAdd(&sq1[g * 256 + ch], vq);
      }
    }
  }
}

// kfin: emit rstd and nmr = -mean*rstd  (consumer does h = fma(y, rstd, nmr))
__global__ void kfin(const float* __restrict__ sum, const float* __restrict__ sq,
                     const unsigned int* __restrict__ hist,
                     float* __restrict__ rstdA, float* __restrict__ nmrA, int C){
  int i = blockIdx.x * blockDim.x + threadIdx.x;
  if (i >= NG * C) return;
  int g = i / C;
  float cnt = fmaxf((float)hist[g], 1.0f);
  float m = sum[i] / cnt;
  float v = sq[i] / cnt - m * m;
  float r = rsqrtf(fmaxf(v, 0.f) + EPSI);
  rstdA[i] = r;
  nmrA[i] = -m * r;
}

// ------- fused: norm+ReLU L1 -> GEMM2 -> y2 (nontemporal) + y2 stats (LDS window) -------
// Each block owns a CONTIGUOUS tile range so its graphs fit an 8-slot LDS window.
__global__ void __launch_bounds__(256) kmain(const __bf16* __restrict__ PQh,
    const unsigned short* __restrict__ W2F, const int4* __restrict__ einfo,
    const float* __restrict__ rstd1, const float* __restrict__ nmr1,
    const float* __restrict__ b2, __bf16* __restrict__ y2h,
    float* __restrict__ sum2, float* __restrict__ sq2, int E, int tpb){
  __shared__ __bf16 tileA[64][264];  // stride 264: 2-way LDS aliasing only (free)
  __shared__ int sgraph[64];
  __shared__ float lsum[8][64];
  __shared__ float lsq[8][64];
  int tid = threadIdx.x;
  for (int i = tid; i < 8 * 64; i += 256){ ((float*)lsum)[i] = 0.f; ((float*)lsq)[i] = 0.f; }
  int nt = (E + 63) >> 6;
  int tb0 = blockIdx.x * tpb;
  int tb1 = min(nt, tb0 + tpb);
  if (tb0 >= nt) return;
  int gbase = einfo[tb0 * 64].z;
  int wave = tid >> 6, lane = tid & 63;
  int quad = lane >> 4, l15 = lane & 15;
  int eo = lane >> 5;         // pair slot for stage-1
  int c8 = (lane & 31) * 8;   // 8-channel slice for stage-1
  ABFrag bk[8];
  #pragma unroll
  for (int ks = 0; ks < 8; ++ks)
    bk[ks].q = *(const uint4*)(W2F + ((size_t)(wave * 8 + ks) * 64 + lane) * 8);
  int cc = wave * 16 + l15;
  float bias2 = b2[cc];
  float s = 0.f, q = 0.f;
  int curg = -1;
  auto flushrun = [&](){
    if (curg >= 0){
      unsigned slot = (unsigned)(curg - gbase);
      if (slot < 8u){
        atomicAdd(&lsum[slot][cc], s);
        atomicAdd(&lsq[slot][cc], q);
      } else {
        atomicAdd(&sum2[curg * 64 + cc], s);
        atomicAdd(&sq2[curg * 64 + cc], q);
      }
      s = 0.f; q = 0.f;
    }
  };
  __syncthreads();
  for (int tb = tb0; tb < tb1; ++tb){
    int p0 = tb * 64;
    // ---- stage 1: batched loads (8 einfo, then 16 gathers in flight per lane) ----
    int4 ev[8];
    #pragma unroll
    for (int j = 0; j < 8; ++j){
      int p = p0 + wave * 16 + j * 2 + eo;
      ev[j] = einfo[min(p, E - 1)];
      if (p >= E) ev[j].z = -1;
    }
    BF8 pu[8], qu[8];
    #pragma unroll
    for (int j = 0; j < 8; ++j){
      pu[j].v = *(const bf16x8*)(PQh + (size_t)ev[j].x * 512 + c8);
      qu[j].v = *(const bf16x8*)(PQh + (size_t)ev[j].y * 512 + 256 + c8);
    }
    #pragma unroll
    for (int j = 0; j < 8; ++j){
      int le = wave * 16 + j * 2 + eo;
      BF8 hv; hv.q = make_uint4(0, 0, 0, 0);
      if (ev[j].z >= 0){
        float rr[8], nn[8];
        *(float4*)&rr[0] = *(const float4*)(rstd1 + ev[j].z * 256 + c8);
        *(float4*)&rr[4] = *(const float4*)(rstd1 + ev[j].z * 256 + c8 + 4);
        *(float4*)&nn[0] = *(const float4*)(nmr1 + ev[j].z * 256 + c8);
        *(float4*)&nn[4] = *(const float4*)(nmr1 + ev[j].z * 256 + c8 + 4);
        #pragma unroll
        for (int t = 0; t < 8; ++t){
          float y = (float)pu[j].v[t] + (float)qu[j].v[t];
          hv.v[t] = (__bf16)fmaxf(0.f, fmaf(y, rr[t], nn[t]));
        }
      }
      if ((lane & 31) == 0) sgraph[le] = ev[j].z;
      *(uint4*)&tileA[le][c8] = hv.q;
    }
    __syncthreads();
    // ---- stage 2: MFMA ----
    f32x4 acc[4];
    #pragma unroll
    for (int eg = 0; eg < 4; ++eg){ acc[eg][0]=0.f; acc[eg][1]=0.f; acc[eg][2]=0.f; acc[eg][3]=0.f; }
    #pragma unroll
    for (int eg = 0; eg < 4; ++eg)
      #pragma unroll
      for (int ks = 0; ks < 8; ++ks){
        ABFrag a;
        a.q = *(const uint4*)&tileA[eg * 16 + l15][ks * 32 + quad * 8];
        acc[eg] = __builtin_amdgcn_mfma_f32_16x16x32_bf16(a.v, bk[ks].v, acc[eg], 0, 0, 0);
      }
    // ---- epilogue: nontemporal y2 store + per-graph stats from fp32 accs ----
    #pragma unroll
    for (int eg = 0; eg < 4; ++eg)
      #pragma unroll
      for (int r = 0; r < 4; ++r){
        int row = eg * 16 + quad * 4 + r;
        int g = sgraph[row];
        if (g >= 0){
          int p = p0 + row;
          float v = acc[eg][r] + bias2;
          union { __bf16 h; unsigned short u; } cv; cv.h = (__bf16)v;
          __builtin_nontemporal_store(cv.u, (unsigned short*)(y2h + (size_t)p * 64 + cc));
          if (g != curg){ flushrun(); curg = g; }
          s += v; q = fmaf(v, v, q);
        }
      }
    __syncthreads();
  }
  flushrun();
  __syncthreads();
  for (int i = tid; i < 8 * 64; i += 256){
    int slot = i >> 6, ch = i & 63;
    float vs = lsum[slot][ch], vq = lsq[slot][ch];
    if (vs != 0.f || vq != 0.f){
      int g = gbase + slot;
      if (g < NG){
        atomicAdd(&sum2[g * 64 + ch], vs);
        atomicAdd(&sq2[g * 64 + ch], vq);
      }
    }
  }
}

// ------- final: norm+ReLU L2 -> GEMV W3 -> scatter; 8 lanes per edge + shuffle reduce -------
__global__ void kfinal(const __bf16* __restrict__ y2h, const int4* __restrict__ einfo,
                       const float* __restrict__ rstd2, const float* __restrict__ nmr2,
                       const float* __restrict__ W3, const float* __restrict__ b3,
                       float* __restrict__ out, int E){
  int sub = threadIdx.x & 7;
  int c8 = sub * 8;
  float w3r[8];
  #pragma unroll
  for (int t = 0; t < 8; ++t) w3r[t] = W3[c8 + t];
  float b3v = b3[0];
  int step = (gridDim.x * blockDim.x) >> 3;
  for (int i = (blockIdx.x * blockDim.x + threadIdx.x) >> 3; i < E; i += step){
    int4 ev = einfo[i];
    BF8 yv; yv.v = *(const bf16x8*)(y2h + (size_t)i * 64 + c8);
    float rr[8], nn[8];
    *(float4*)&rr[0] = *(const float4*)(rstd2 + ev.z * 64 + c8);
    *(float4*)&rr[4] = *(const float4*)(rstd2 + ev.z * 64 + c8 + 4);
    *(float4*)&nn[0] = *(const float4*)(nmr2 + ev.z * 64 + c8);
    *(float4*)&nn[4] = *(const float4*)(nmr2 + ev.z * 64 + c8 + 4);
    float a = 0.f;
    #pragma unroll
    for (int t = 0; t < 8; ++t)
      a += fmaxf(0.f, fmaf((float)yv.v[t], rr[t], nn[t])) * w3r[t];
    a += __shfl_xor(a, 1);
    a += __shfl_xor(a, 2);
    a += __shfl_xor(a, 4);
    if (sub == 0) out[ev.w] = a + b3v;
  }
}

extern "C" void kernel_launch(void* const* d_in, const int* in_sizes, int n_in,
                              void* d_out, int out_size, void* d_ws, size_t ws_size,
                              hipStream_t stream){
  const float* emb  = (const float*)d_in[0];
  const int*   ei   = (const int*)d_in[1];
  const int*   batch= (const int*)d_in[2];
  const float* W1   = (const float*)d_in[3];
  const float* b1   = (const float*)d_in[4];
  const float* W2   = (const float*)d_in[5];
  const float* b2   = (const float*)d_in[6];
  const float* W3   = (const float*)d_in[7];
  const float* b3   = (const float*)d_in[8];
  int N = in_sizes[0] / 64;
  int E = in_sizes[1] / 2;
  float* out = (float*)d_out;

  char* w = (char*)d_ws;
  size_t off = 0;
  auto nxt = [&](size_t bytes) -> char* {
    char* p = w + off;
    off = (off + bytes + 255) & ~(size_t)255;
    return p;
  };
  __bf16* embb = (__bf16*)nxt((size_t)N * 64 * 2);
  unsigned short* WcF  = (unsigned short*)nxt(32 * 2 * 64 * 8 * 2);
  unsigned short* W2F  = (unsigned short*)nxt(4 * 8 * 64 * 8 * 2);
  __bf16* PQh  = (__bf16*)nxt((size_t)N * 512 * 2);
  __bf16* y2h  = (__bf16*)nxt((size_t)E * 64 * 2);
  int4* einfo = (int4*)nxt((size_t)E * 16);
  float* rstd1 = (float*)nxt(NG * 256 * 4);
  float* nmr1  = (float*)nxt(NG * 256 * 4);
  float* rstd2 = (float*)nxt(NG * 64 * 4);
  float* nmr2  = (float*)nxt(NG * 64 * 4);
  unsigned int* ncursor = (unsigned int*)nxt((size_t)N * 4);
  // zero-init region (contiguous, one memset)
  char* zbase = w + off;
  unsigned int* hist  = (unsigned int*)nxt(NG * 4);
  unsigned int* nodeh = (unsigned int*)nxt((size_t)N * 4);
  float* sum1 = (float*)nxt(NG * 256 * 4);
  float* sq1  = (float*)nxt(NG * 256 * 4);
  float* sum2 = (float*)nxt(NG * 64 * 4);
  float* sq2  = (float*)nxt(NG * 64 * 4);
  size_t zbytes = (size_t)((w + off) - zbase);
  hipMemsetAsync(zbase, 0, zbytes, stream);

  kprep<<<2048, 256, 0, stream>>>(emb, W1, W2, ei, batch, embb, WcF, W2F, hist, nodeh, N, E);
  kscan<<<1, 1024, 0, stream>>>(nodeh, ncursor, N);
  {
    int scatBlocks = (E + 255) / 256;
    int gemmBlocks = (((N + 15) / 16) * 32 + 3) / 4;
    kfused<<<scatBlocks + gemmBlocks, 256, 0, stream>>>(ei, batch, ncursor, einfo, E,
                                                        embb, WcF, b1, PQh, N, scatBlocks);
  }
  kstats1<<<(E + 511) / 512, 256, 0, stream>>>(PQh, einfo, E, sum1, sq1);
  kfin<<<(NG * 256 + 255) / 256, 256, 0, stream>>>(sum1, sq1, hist, rstd1, nmr1, 256);
  {
    int nt = (E + 63) / 64;
    int NB = 2048;
    int tpb = (nt + NB - 1) / NB;
    kmain<<<NB, 256, 0, stream>>>(PQh, W2F, einfo, rstd1, nmr1, b2, y2h, sum2, sq2, E, tpb);
  }
  kfin<<<(NG * 64 + 255) / 256, 256, 0, stream>>>(sum2, sq2, hist, rstd2, nmr2, 64);
  kfinal<<<2048, 256, 0, stream>>>(y2h, einfo, rstd2, nmr2, W3, b3, out, E);
}